// Round 1
// baseline (353.759 us; speedup 1.0000x reference)
//
#include <hip/hip_runtime.h>
#include <hip/hip_bf16.h>
#include <cstdint>
#include <cstddef>

typedef __bf16 y8 __attribute__((ext_vector_type(8)));
typedef float f4 __attribute__((ext_vector_type(4)));
typedef unsigned short u16t;

#define NB 4
#define TT 2048
#define DD 1024
#define HH 16

static constexpr size_t OUT0 = (size_t)NB * TT * DD;  // 8388608 floats (out), then present

__device__ __forceinline__ u16t bf16r(float f) {
    union { float f; unsigned u; } x; x.f = f;
    return (u16t)((x.u + 0x7FFFu + ((x.u >> 16) & 1u)) >> 16);
}

#define GLDS16(g, s) __builtin_amdgcn_global_load_lds( \
    (__attribute__((address_space(1))) void*)(g),      \
    (__attribute__((address_space(3))) void*)(s), 16, 0, 0)

// ---------------------------------------------------------------- conversions
__global__ __launch_bounds__(256)
void cvt_f32_bf16(const float* __restrict__ in, u16t* __restrict__ outp, int n) {
    int i = (blockIdx.x * 256 + threadIdx.x) * 8;
    if (i >= n) return;
    float4 a = *(const float4*)(in + i);
    float4 b = *(const float4*)(in + i + 4);
    union { u16t h[8]; uint4 q; } u;
    u.h[0] = bf16r(a.x); u.h[1] = bf16r(a.y); u.h[2] = bf16r(a.z); u.h[3] = bf16r(a.w);
    u.h[4] = bf16r(b.x); u.h[5] = bf16r(b.y); u.h[6] = bf16r(b.z); u.h[7] = bf16r(b.w);
    *(uint4*)(outp + i) = u.q;
}

// in: (Kd, Nd) f32 row-major -> out: (Nd, Kd) bf16 row-major
__global__ __launch_bounds__(256)
void transpose_w(const float* __restrict__ in, u16t* __restrict__ outp, int Kd, int Nd) {
    __shared__ float tile[32][33];
    const int n0 = blockIdx.x * 32, k0 = blockIdx.y * 32;
    const int tx = threadIdx.x & 31, ty = threadIdx.x >> 5;
    for (int yy = ty; yy < 32; yy += 8)
        tile[yy][tx] = in[(size_t)(k0 + yy) * Nd + n0 + tx];
    __syncthreads();
    for (int yy = ty; yy < 32; yy += 8)
        outp[(size_t)(n0 + yy) * Kd + k0 + tx] = bf16r(tile[tx][yy]);
}

// vb: (BH, T, 64) bf16 -> vt: (BH, 64, T) bf16
__global__ __launch_bounds__(256)
void transpose_v(const u16t* __restrict__ vb, u16t* __restrict__ vt) {
    __shared__ u16t tile[32][33];
    const int t0 = blockIdx.x * 32, d0 = blockIdx.y * 32, bh = blockIdx.z;
    const u16t* src = vb + (size_t)bh * TT * 64;
    u16t* dst = vt + (size_t)bh * 64 * TT;
    const int tx = threadIdx.x & 31, ty = threadIdx.x >> 5;
    for (int yy = ty; yy < 32; yy += 8)
        tile[yy][tx] = src[(t0 + yy) * 64 + d0 + tx];
    __syncthreads();
    for (int yy = ty; yy < 32; yy += 8)
        dst[(d0 + yy) * TT + t0 + tx] = tile[tx][yy];
}

// ---------------------------------------------------------------- GEMM
// C(M,N) f32 = A(M,K)bf16 * Bt(N,K)bf16^T + bias.
// MODE 0: plain f32 C.  MODE 1: qkv epilogue (present f32 + head-layout bf16 q/k/v).
template<int MODE>
__global__ __launch_bounds__(256)
void gemm_bt(const u16t* __restrict__ A, const u16t* __restrict__ Bt,
             const float* __restrict__ bias, float* __restrict__ C,
             float* __restrict__ pres, u16t* __restrict__ qb,
             u16t* __restrict__ kb, u16t* __restrict__ vb,
             int M, int N, int K)
{
    __shared__ u16t ldsA[128 * 64];
    __shared__ u16t ldsB[128 * 64];
    const int tid = threadIdx.x;
    const int w = tid >> 6, l = tid & 63;
    const int wr = w >> 1, wc = w & 1;
    const int lr = l & 15, lq = l >> 4;
    const int bm = blockIdx.x * 128;
    const int bn = blockIdx.y * 128;

    f4 acc[4][4] = {};

    for (int k0 = 0; k0 < K; k0 += 64) {
        __syncthreads();
#pragma unroll
        for (int c = 0; c < 4; ++c) {
            const int L = ((w * 64 + l) << 4) + (c << 12);
            const int row = L >> 7;
            const int col = (((L >> 4) & 7) ^ (row & 7)) << 3;  // inverse-swizzled source
            GLDS16(A + (size_t)(bm + row) * K + k0 + col, (char*)ldsA + (w << 10) + (c << 12));
            GLDS16(Bt + (size_t)(bn + row) * K + k0 + col, (char*)ldsB + (w << 10) + (c << 12));
        }
        __syncthreads();
#pragma unroll
        for (int ks = 0; ks < 2; ++ks) {
            y8 af[4], bfv[4];
#pragma unroll
            for (int m = 0; m < 4; ++m) {
                const int row = wr * 64 + m * 16 + lr;
                const int slot = (lq + ks * 4) ^ (row & 7);
                af[m] = *(const y8*)((const char*)ldsA + row * 128 + (slot << 4));
            }
#pragma unroll
            for (int n = 0; n < 4; ++n) {
                const int row = wc * 64 + n * 16 + lr;
                const int slot = (lq + ks * 4) ^ (row & 7);
                bfv[n] = *(const y8*)((const char*)ldsB + row * 128 + (slot << 4));
            }
#pragma unroll
            for (int m = 0; m < 4; ++m)
#pragma unroll
                for (int n = 0; n < 4; ++n)
                    acc[m][n] = __builtin_amdgcn_mfma_f32_16x16x32_bf16(af[m], bfv[n], acc[m][n], 0, 0, 0);
        }
    }

    if (MODE == 0) {
#pragma unroll
        for (int m = 0; m < 4; ++m) {
            const int rowb = bm + wr * 64 + m * 16 + 4 * lq;
#pragma unroll
            for (int n = 0; n < 4; ++n) {
                const int col = bn + wc * 64 + n * 16 + lr;
                const float bv = bias[col];
#pragma unroll
                for (int r = 0; r < 4; ++r)
                    C[(size_t)(rowb + r) * N + col] = acc[m][n][r] + bv;
            }
        }
    } else {
        const int part = bn >> 10;  // 0=q, 1=k, 2=v (128-col tiles never cross 1024 boundary)
#pragma unroll
        for (int m = 0; m < 4; ++m) {
            const int rowb = bm + wr * 64 + m * 16 + 4 * lq;
#pragma unroll
            for (int n = 0; n < 4; ++n) {
                const int colg = bn + wc * 64 + n * 16 + lr;
                const float bv = bias[colg];
                const int cl = colg & 1023;
                const int h = cl >> 6, d = cl & 63;
#pragma unroll
                for (int r = 0; r < 4; ++r) {
                    const int bt = rowb + r;
                    const int b = bt >> 11, t = bt & 2047;
                    const float val = acc[m][n][r] + bv;
                    const size_t hidx = (((size_t)(b * HH + h)) * TT + t) * 64 + d;
                    if (part == 0) {
                        qb[hidx] = bf16r(val);
                    } else if (part == 1) {
                        kb[hidx] = bf16r(val);
                        pres[OUT0 + (((size_t)((b * 2 + 0) * HH + h)) * TT + t) * 64 + d] = val;
                    } else {
                        vb[hidx] = bf16r(val);
                        pres[OUT0 + (((size_t)((b * 2 + 1) * HH + h)) * TT + t) * 64 + d] = val;
                    }
                }
            }
        }
    }
}

// ---------------------------------------------------------------- attention
// Block = (qt, bh): 64 q-rows, 4 waves x 16 rows. KV tile 64. Flash online softmax.
__global__ __launch_bounds__(256)
void attn_fwd(const u16t* __restrict__ qg, const u16t* __restrict__ kg,
              const u16t* __restrict__ vtg, u16t* __restrict__ og)
{
    __shared__ u16t sQ[64 * 64], sK[64 * 64], sV[64 * 64], sP[4 * 16 * 64];
    const int tid = threadIdx.x;
    const int w = tid >> 6, l = tid & 63;
    const int lr = l & 15, lq = l >> 4;
    const int qt = blockIdx.x;
    const int bh = blockIdx.y;
    const int b = bh >> 4, h = bh & 15;
    const u16t* qsrc = qg + (size_t)bh * TT * 64;
    const u16t* ksrc = kg + (size_t)bh * TT * 64;
    const u16t* vsrc = vtg + (size_t)bh * 64 * TT;

    // stage Q tile (64 x 64), swizzled
#pragma unroll
    for (int c = 0; c < 2; ++c) {
        const int L = ((w * 64 + l) << 4) + (c << 12);
        const int row = L >> 7;
        const int col = (((L >> 4) & 7) ^ (row & 7)) << 3;
        GLDS16(qsrc + (qt * 64 + row) * 64 + col, (char*)sQ + (w << 10) + (c << 12));
    }
    __syncthreads();
    y8 qf[2];
#pragma unroll
    for (int ks = 0; ks < 2; ++ks) {
        const int row = w * 16 + lr;
        const int slot = (lq + ks * 4) ^ (row & 7);
        qf[ks] = *(const y8*)((const char*)sQ + row * 128 + (slot << 4));
    }

    f4 o[4] = {};
    float mrow[4], lsum[4];
#pragma unroll
    for (int r = 0; r < 4; ++r) { mrow[r] = -1e30f; lsum[r] = 0.f; }

    char* Pw = (char*)sP + (w << 11);  // per-wave 16x64 bf16 region

    for (int kt = 0; kt <= qt; ++kt) {
        const int kv0 = kt * 64;
        __syncthreads();
#pragma unroll
        for (int c = 0; c < 2; ++c) {
            const int L = ((w * 64 + l) << 4) + (c << 12);
            const int row = L >> 7;
            const int col = (((L >> 4) & 7) ^ (row & 7)) << 3;
            GLDS16(ksrc + (kv0 + row) * 64 + col, (char*)sK + (w << 10) + (c << 12));
            GLDS16(vsrc + (size_t)row * TT + kv0 + col, (char*)sV + (w << 10) + (c << 12));
        }
        __syncthreads();

        // S = Q K^T  (16 q-rows x 64 keys per wave)
        f4 s[4] = {};
#pragma unroll
        for (int ks = 0; ks < 2; ++ks) {
#pragma unroll
            for (int n = 0; n < 4; ++n) {
                const int row = n * 16 + lr;
                const int slot = (lq + ks * 4) ^ (row & 7);
                const y8 kf = *(const y8*)((const char*)sK + row * 128 + (slot << 4));
                s[n] = __builtin_amdgcn_mfma_f32_16x16x32_bf16(qf[ks], kf, s[n], 0, 0, 0);
            }
        }

        const bool diag = (kt == qt);
#pragma unroll
        for (int n = 0; n < 4; ++n) {
#pragma unroll
            for (int r = 0; r < 4; ++r) {
                float sv = s[n][r] * 0.125f;
                if (diag && (n * 16 + lr > w * 16 + 4 * lq + r)) sv = -1e30f;
                s[n][r] = sv;
            }
        }

        // online softmax (row lives across the 16-lane group, 4 col-groups, 4 regs)
#pragma unroll
        for (int r = 0; r < 4; ++r) {
            float mx = fmaxf(fmaxf(s[0][r], s[1][r]), fmaxf(s[2][r], s[3][r]));
            mx = fmaxf(mx, __shfl_xor(mx, 1));
            mx = fmaxf(mx, __shfl_xor(mx, 2));
            mx = fmaxf(mx, __shfl_xor(mx, 4));
            mx = fmaxf(mx, __shfl_xor(mx, 8));
            const float newm = fmaxf(mrow[r], mx);
            const float corr = __expf(mrow[r] - newm);
            mrow[r] = newm;
            float rs = 0.f;
#pragma unroll
            for (int n = 0; n < 4; ++n) {
                const float p = __expf(s[n][r] - newm);
                s[n][r] = p;
                rs += p;
            }
            rs += __shfl_xor(rs, 1);
            rs += __shfl_xor(rs, 2);
            rs += __shfl_xor(rs, 4);
            rs += __shfl_xor(rs, 8);
            lsum[r] = lsum[r] * corr + rs;
            o[0][r] *= corr; o[1][r] *= corr; o[2][r] *= corr; o[3][r] *= corr;
        }

        // P -> per-wave LDS (bf16, swizzled rows)
#pragma unroll
        for (int n = 0; n < 4; ++n) {
#pragma unroll
            for (int r = 0; r < 4; ++r) {
                const int prow = 4 * lq + r;
                const int pb = (n * 16 + lr) * 2;
                const int boff = prow * 128 + (((pb >> 4) ^ (prow & 7)) << 4) + (pb & 15);
                *(u16t*)(Pw + boff) = bf16r(s[n][r]);
            }
        }

        // O += P V   (A-frag from per-wave P, B-frag from Vt)
#pragma unroll
        for (int ks = 0; ks < 2; ++ks) {
            const int slotp = (lq + ks * 4) ^ (lr & 7);
            const y8 pf = *(const y8*)(Pw + lr * 128 + (slotp << 4));
#pragma unroll
            for (int n = 0; n < 4; ++n) {
                const int row = n * 16 + lr;
                const int slot = (lq + ks * 4) ^ (row & 7);
                const y8 vf = *(const y8*)((const char*)sV + row * 128 + (slot << 4));
                o[n] = __builtin_amdgcn_mfma_f32_16x16x32_bf16(pf, vf, o[n], 0, 0, 0);
            }
        }
    }

#pragma unroll
    for (int n = 0; n < 4; ++n) {
#pragma unroll
        for (int r = 0; r < 4; ++r) {
            const int t = qt * 64 + w * 16 + 4 * lq + r;
            const float val = o[n][r] / lsum[r];
            og[((size_t)(b * TT + t)) * DD + h * 64 + n * 16 + lr] = bf16r(val);
        }
    }
}

// ---------------------------------------------------------------- launch
extern "C" void kernel_launch(void* const* d_in, const int* in_sizes, int n_in,
                              void* d_out, int out_size, void* d_ws, size_t ws_size,
                              hipStream_t stream) {
    const float* x      = (const float*)d_in[0];
    const float* w_attn = (const float*)d_in[1];
    const float* b_attn = (const float*)d_in[2];
    const float* w_proj = (const float*)d_in[3];
    const float* b_proj = (const float*)d_in[4];
    float* outp = (float*)d_out;
    char* ws = (char*)d_ws;

    // workspace layout (bytes)
    u16t* xb  = (u16t*)(ws + 0);          // 8192x1024 bf16 (x, later reused as attn_out)
    u16t* wta = (u16t*)(ws + 16777216);   // 3072x1024 bf16 (w_attn^T)
    u16t* wtp = (u16t*)(ws + 23068672);   // 1024x1024 bf16 (w_proj^T)
    u16t* qb  = (u16t*)(ws + 25165824);   // (B,H,T,64) bf16
    u16t* kb  = (u16t*)(ws + 41943040);   // (B,H,T,64) bf16
    u16t* vb  = (u16t*)(ws + 58720256);   // (B,H,T,64) bf16
    u16t* vtb = (u16t*)(ws + 75497472);   // (B,H,64,T) bf16
    if (ws_size < 92274688) return;       // loud failure rather than OOB writes

    cvt_f32_bf16<<<4096, 256, 0, stream>>>(x, xb, 8388608);
    transpose_w<<<dim3(96, 32), 256, 0, stream>>>(w_attn, wta, 1024, 3072);
    transpose_w<<<dim3(32, 32), 256, 0, stream>>>(w_proj, wtp, 1024, 1024);

    gemm_bt<1><<<dim3(64, 24), 256, 0, stream>>>(xb, wta, b_attn, nullptr, outp,
                                                 qb, kb, vb, 8192, 3072, 1024);
    transpose_v<<<dim3(64, 2, 64), 256, 0, stream>>>(vb, vtb);
    attn_fwd<<<dim3(32, 64), 256, 0, stream>>>(qb, kb, vtb, xb /* reuse as attn_out */);
    gemm_bt<0><<<dim3(64, 8), 256, 0, stream>>>(xb, wtp, b_proj, outp,
                                                nullptr, nullptr, nullptr, nullptr,
                                                8192, 1024, 1024);
}

// Round 2
// 230.088 us; speedup vs baseline: 1.5375x; 1.5375x over previous
//
#include <hip/hip_runtime.h>
#include <hip/hip_bf16.h>
#include <cstdint>
#include <cstddef>

typedef __bf16 y8 __attribute__((ext_vector_type(8)));
typedef float f4 __attribute__((ext_vector_type(4)));
typedef unsigned short u16t;

#define NB 4
#define TT 2048
#define DD 1024
#define HH 16

static constexpr size_t OUT0 = (size_t)NB * TT * DD;  // 8388608 floats (out), then present

__device__ __forceinline__ u16t bf16r(float f) {
    union { float f; unsigned u; } x; x.f = f;
    return (u16t)((x.u + 0x7FFFu + ((x.u >> 16) & 1u)) >> 16);
}

#define GLDS16(g, s) __builtin_amdgcn_global_load_lds( \
    (__attribute__((address_space(1))) void*)(g),      \
    (__attribute__((address_space(3))) void*)(s), 16, 0, 0)

// ---------------------------------------------------------------- conversions
__global__ __launch_bounds__(256)
void cvt_f32_bf16(const float* __restrict__ in, u16t* __restrict__ outp, int n) {
    int i = (blockIdx.x * 256 + threadIdx.x) * 8;
    if (i >= n) return;
    float4 a = *(const float4*)(in + i);
    float4 b = *(const float4*)(in + i + 4);
    union { u16t h[8]; uint4 q; } u;
    u.h[0] = bf16r(a.x); u.h[1] = bf16r(a.y); u.h[2] = bf16r(a.z); u.h[3] = bf16r(a.w);
    u.h[4] = bf16r(b.x); u.h[5] = bf16r(b.y); u.h[6] = bf16r(b.z); u.h[7] = bf16r(b.w);
    *(uint4*)(outp + i) = u.q;
}

// in: (Kd, Nd) f32 row-major -> out: (Nd, Kd) bf16 row-major
__global__ __launch_bounds__(256)
void transpose_w(const float* __restrict__ in, u16t* __restrict__ outp, int Kd, int Nd) {
    __shared__ float tile[32][33];
    const int n0 = blockIdx.x * 32, k0 = blockIdx.y * 32;
    const int tx = threadIdx.x & 31, ty = threadIdx.x >> 5;
    for (int yy = ty; yy < 32; yy += 8)
        tile[yy][tx] = in[(size_t)(k0 + yy) * Nd + n0 + tx];
    __syncthreads();
    for (int yy = ty; yy < 32; yy += 8)
        outp[(size_t)(n0 + yy) * Kd + k0 + tx] = bf16r(tile[tx][yy]);
}

// vb: (BH, T, 64) bf16 -> vt: (BH, 64, T) bf16
__global__ __launch_bounds__(256)
void transpose_v(const u16t* __restrict__ vb, u16t* __restrict__ vt) {
    __shared__ u16t tile[32][33];
    const int t0 = blockIdx.x * 32, d0 = blockIdx.y * 32, bh = blockIdx.z;
    const u16t* src = vb + (size_t)bh * TT * 64;
    u16t* dst = vt + (size_t)bh * 64 * TT;
    const int tx = threadIdx.x & 31, ty = threadIdx.x >> 5;
    for (int yy = ty; yy < 32; yy += 8)
        tile[yy][tx] = src[(t0 + yy) * 64 + d0 + tx];
    __syncthreads();
    for (int yy = ty; yy < 32; yy += 8)
        dst[(d0 + yy) * TT + t0 + tx] = tile[tx][yy];
}

// ---------------------------------------------------------------- GEMM
// C(M,N) f32 = A(M,K)bf16 * Bt(N,K)bf16^T + bias.
// MODE 0: plain f32 C.  MODE 1: qkv epilogue (present f32 + head-layout bf16 q/k/v).
template<int MODE>
__global__ __launch_bounds__(256)
void gemm_bt(const u16t* __restrict__ A, const u16t* __restrict__ Bt,
             const float* __restrict__ bias, float* __restrict__ C,
             float* __restrict__ pres, u16t* __restrict__ qb,
             u16t* __restrict__ kb, u16t* __restrict__ vb,
             int M, int N, int K)
{
    __shared__ u16t ldsA[128 * 64];
    __shared__ u16t ldsB[128 * 64];
    const int tid = threadIdx.x;
    const int w = tid >> 6, l = tid & 63;
    const int wr = w >> 1, wc = w & 1;
    const int lr = l & 15, lq = l >> 4;
    const int bm = blockIdx.x * 128;
    const int bn = blockIdx.y * 128;

    f4 acc[4][4] = {};

    for (int k0 = 0; k0 < K; k0 += 64) {
        __syncthreads();
#pragma unroll
        for (int c = 0; c < 4; ++c) {
            const int L = ((w * 64 + l) << 4) + (c << 12);
            const int row = L >> 7;
            const int col = (((L >> 4) & 7) ^ (row & 7)) << 3;  // inverse-swizzled source
            GLDS16(A + (size_t)(bm + row) * K + k0 + col, (char*)ldsA + (w << 10) + (c << 12));
            GLDS16(Bt + (size_t)(bn + row) * K + k0 + col, (char*)ldsB + (w << 10) + (c << 12));
        }
        __syncthreads();
#pragma unroll
        for (int ks = 0; ks < 2; ++ks) {
            y8 af[4], bfv[4];
#pragma unroll
            for (int m = 0; m < 4; ++m) {
                const int row = wr * 64 + m * 16 + lr;
                const int slot = (lq + ks * 4) ^ (row & 7);
                af[m] = *(const y8*)((const char*)ldsA + row * 128 + (slot << 4));
            }
#pragma unroll
            for (int n = 0; n < 4; ++n) {
                const int row = wc * 64 + n * 16 + lr;
                const int slot = (lq + ks * 4) ^ (row & 7);
                bfv[n] = *(const y8*)((const char*)ldsB + row * 128 + (slot << 4));
            }
#pragma unroll
            for (int m = 0; m < 4; ++m)
#pragma unroll
                for (int n = 0; n < 4; ++n)
                    acc[m][n] = __builtin_amdgcn_mfma_f32_16x16x32_bf16(af[m], bfv[n], acc[m][n], 0, 0, 0);
        }
    }

    if (MODE == 0) {
#pragma unroll
        for (int m = 0; m < 4; ++m) {
            const int rowb = bm + wr * 64 + m * 16 + 4 * lq;
#pragma unroll
            for (int n = 0; n < 4; ++n) {
                const int col = bn + wc * 64 + n * 16 + lr;
                const float bv = bias[col];
#pragma unroll
                for (int r = 0; r < 4; ++r)
                    C[(size_t)(rowb + r) * N + col] = acc[m][n][r] + bv;
            }
        }
    } else {
        const int part = bn >> 10;  // 0=q, 1=k, 2=v (128-col tiles never cross 1024 boundary)
#pragma unroll
        for (int m = 0; m < 4; ++m) {
            const int rowb = bm + wr * 64 + m * 16 + 4 * lq;
#pragma unroll
            for (int n = 0; n < 4; ++n) {
                const int colg = bn + wc * 64 + n * 16 + lr;
                const float bv = bias[colg];
                const int cl = colg & 1023;
                const int h = cl >> 6, d = cl & 63;
#pragma unroll
                for (int r = 0; r < 4; ++r) {
                    const int bt = rowb + r;
                    const int b = bt >> 11, t = bt & 2047;
                    const float val = acc[m][n][r] + bv;
                    const size_t hidx = (((size_t)(b * HH + h)) * TT + t) * 64 + d;
                    if (part == 0) {
                        qb[hidx] = bf16r(val);
                    } else if (part == 1) {
                        kb[hidx] = bf16r(val);
                        pres[OUT0 + (((size_t)((b * 2 + 0) * HH + h)) * TT + t) * 64 + d] = val;
                    } else {
                        vb[hidx] = bf16r(val);
                        pres[OUT0 + (((size_t)((b * 2 + 1) * HH + h)) * TT + t) * 64 + d] = val;
                    }
                }
            }
        }
    }
}

// ---------------------------------------------------------------- attention
// Block = (qt, bh): 128 q-rows, 4 waves x 32 rows (2 m-tiles each). KV tile 64,
// double-buffered (1 barrier per tile). Flash online softmax; lsum reduce deferred
// to epilogue (per-lane partials, row-uniform corr).
__global__ __launch_bounds__(256, 2)
void attn_fwd(const u16t* __restrict__ qg, const u16t* __restrict__ kg,
              const u16t* __restrict__ vtg, u16t* __restrict__ og)
{
    __shared__ u16t sQ[128 * 64];      // 16 KB
    __shared__ u16t sK[2 * 64 * 64];   // 16 KB (double buffer)
    __shared__ u16t sV[2 * 64 * 64];   // 16 KB
    __shared__ u16t sP[4 * 32 * 64];   // 16 KB (per-wave 32x64)
    const int tid = threadIdx.x;
    const int w = tid >> 6, l = tid & 63;
    const int lr = l & 15, lq = l >> 4;
    const int qt = 15 - blockIdx.y;    // long blocks first
    const int bh = blockIdx.x;
    const int b = bh >> 4, h = bh & 15;
    const u16t* qsrc = qg + (size_t)bh * TT * 64;
    const u16t* ksrc = kg + (size_t)bh * TT * 64;
    const u16t* vsrc = vtg + (size_t)bh * 64 * TT;

    auto stageKV = [&](int kt, int pi) {
        const int kv0 = kt << 6;
#pragma unroll
        for (int c = 0; c < 2; ++c) {
            const int L = ((w * 64 + l) << 4) + (c << 12);
            const int row = L >> 7;
            const int col = (((L >> 4) & 7) ^ (row & 7)) << 3;
            GLDS16(ksrc + (kv0 + row) * 64 + col,
                   (char*)sK + (pi << 13) + (w << 10) + (c << 12));
            GLDS16(vsrc + (size_t)row * TT + kv0 + col,
                   (char*)sV + (pi << 13) + (w << 10) + (c << 12));
        }
    };

    // stage Q tile (128 x 64) + KV tile 0
#pragma unroll
    for (int c = 0; c < 4; ++c) {
        const int L = ((w * 64 + l) << 4) + (c << 12);
        const int row = L >> 7;
        const int col = (((L >> 4) & 7) ^ (row & 7)) << 3;
        GLDS16(qsrc + (qt * 128 + row) * 64 + col, (char*)sQ + (w << 10) + (c << 12));
    }
    stageKV(0, 0);
    __syncthreads();

    y8 qf[2][2];
#pragma unroll
    for (int qm = 0; qm < 2; ++qm)
#pragma unroll
        for (int ks = 0; ks < 2; ++ks) {
            const int row = w * 32 + qm * 16 + lr;
            const int slot = (lq + ks * 4) ^ (row & 7);
            qf[qm][ks] = *(const y8*)((const char*)sQ + row * 128 + (slot << 4));
        }

    f4 o[2][4] = {};
    float mrow[2][4], lsum[2][4];
#pragma unroll
    for (int qm = 0; qm < 2; ++qm)
#pragma unroll
        for (int r = 0; r < 4; ++r) { mrow[qm][r] = -1e30f; lsum[qm][r] = 0.f; }

    char* Pw = (char*)sP + (w << 12);  // per-wave 32x64 bf16 region
    const int qmax = qt * 128 + w * 32 + 31;  // wave's last q-row
    const int ktiles = 2 * qt + 2;
    int cur = 0;

    for (int kt = 0; kt < ktiles; ++kt) {
        __syncthreads();  // buf[cur] staged; all waves done reading buf[cur^1]
        if (kt + 1 < ktiles) stageKV(kt + 1, cur ^ 1);
        const int kv0 = kt << 6;
        if (kv0 <= qmax) {  // tile not fully masked for this wave
            const char* Kb = (const char*)sK + (cur << 13);
            const char* Vb = (const char*)sV + (cur << 13);

            // S = Q K^T  (32 q-rows x 64 keys per wave)
            f4 s[2][4] = {};
#pragma unroll
            for (int ks = 0; ks < 2; ++ks) {
                y8 kf[4];
#pragma unroll
                for (int n = 0; n < 4; ++n) {
                    const int row = n * 16 + lr;
                    const int slot = (lq + ks * 4) ^ (row & 7);
                    kf[n] = *(const y8*)(Kb + row * 128 + (slot << 4));
                }
#pragma unroll
                for (int qm = 0; qm < 2; ++qm)
#pragma unroll
                    for (int n = 0; n < 4; ++n)
                        s[qm][n] = __builtin_amdgcn_mfma_f32_16x16x32_bf16(qf[qm][ks], kf[n], s[qm][n], 0, 0, 0);
            }

#pragma unroll
            for (int qm = 0; qm < 2; ++qm) {
                const int qb0 = qt * 128 + w * 32 + qm * 16;
                if (kv0 + 63 > qb0) {  // tile crosses diagonal for this m-tile
#pragma unroll
                    for (int n = 0; n < 4; ++n) {
                        const int kcol = kv0 + n * 16 + lr;
#pragma unroll
                        for (int r = 0; r < 4; ++r) {
                            const int qrow = qb0 + 4 * lq + r;
                            const float sv = s[qm][n][r] * 0.125f;
                            s[qm][n][r] = (kcol > qrow) ? -1e30f : sv;
                        }
                    }
                } else {
#pragma unroll
                    for (int n = 0; n < 4; ++n)
#pragma unroll
                        for (int r = 0; r < 4; ++r) s[qm][n][r] *= 0.125f;
                }

                // online softmax: max reduce across 16-lane row group; sum stays per-lane
#pragma unroll
                for (int r = 0; r < 4; ++r) {
                    float mx = fmaxf(fmaxf(s[qm][0][r], s[qm][1][r]),
                                     fmaxf(s[qm][2][r], s[qm][3][r]));
                    mx = fmaxf(mx, __shfl_xor(mx, 1));
                    mx = fmaxf(mx, __shfl_xor(mx, 2));
                    mx = fmaxf(mx, __shfl_xor(mx, 4));
                    mx = fmaxf(mx, __shfl_xor(mx, 8));
                    const float newm = fmaxf(mrow[qm][r], mx);
                    const float corr = __expf(mrow[qm][r] - newm);
                    mrow[qm][r] = newm;
                    float rs = 0.f;
#pragma unroll
                    for (int n = 0; n < 4; ++n) {
                        const float p = __expf(s[qm][n][r] - newm);
                        s[qm][n][r] = p;
                        rs += p;
                    }
                    lsum[qm][r] = lsum[qm][r] * corr + rs;
#pragma unroll
                    for (int n = 0; n < 4; ++n) o[qm][n][r] *= corr;
                }

                // P -> per-wave LDS (bf16, swizzled rows)
#pragma unroll
                for (int n = 0; n < 4; ++n)
#pragma unroll
                    for (int r = 0; r < 4; ++r) {
                        const int prow = qm * 16 + 4 * lq + r;
                        const int pb = (n * 16 + lr) * 2;
                        const int boff = prow * 128 + (((pb >> 4) ^ (prow & 7)) << 4) + (pb & 15);
                        *(u16t*)(Pw + boff) = bf16r(s[qm][n][r]);
                    }
            }

            // O += P V
#pragma unroll
            for (int ks = 0; ks < 2; ++ks) {
                y8 vf[4], pf[2];
#pragma unroll
                for (int n = 0; n < 4; ++n) {
                    const int row = n * 16 + lr;
                    const int slot = (lq + ks * 4) ^ (row & 7);
                    vf[n] = *(const y8*)(Vb + row * 128 + (slot << 4));
                }
#pragma unroll
                for (int qm = 0; qm < 2; ++qm) {
                    const int slotp = (lq + ks * 4) ^ (lr & 7);
                    pf[qm] = *(const y8*)(Pw + (qm * 16 + lr) * 128 + (slotp << 4));
                }
#pragma unroll
                for (int qm = 0; qm < 2; ++qm)
#pragma unroll
                    for (int n = 0; n < 4; ++n)
                        o[qm][n] = __builtin_amdgcn_mfma_f32_16x16x32_bf16(pf[qm], vf[n], o[qm][n], 0, 0, 0);
            }
        }
        cur ^= 1;
    }

    // epilogue: deferred lsum reduce + normalize + store
#pragma unroll
    for (int qm = 0; qm < 2; ++qm)
#pragma unroll
        for (int r = 0; r < 4; ++r) {
            float t = lsum[qm][r];
            t += __shfl_xor(t, 1);
            t += __shfl_xor(t, 2);
            t += __shfl_xor(t, 4);
            t += __shfl_xor(t, 8);
            const float inv = 1.0f / t;
            const int trow = qt * 128 + w * 32 + qm * 16 + 4 * lq + r;
#pragma unroll
            for (int n = 0; n < 4; ++n)
                og[((size_t)(b * TT + trow)) * DD + h * 64 + n * 16 + lr] =
                    bf16r(o[qm][n][r] * inv);
        }
}

// ---------------------------------------------------------------- launch
extern "C" void kernel_launch(void* const* d_in, const int* in_sizes, int n_in,
                              void* d_out, int out_size, void* d_ws, size_t ws_size,
                              hipStream_t stream) {
    const float* x      = (const float*)d_in[0];
    const float* w_attn = (const float*)d_in[1];
    const float* b_attn = (const float*)d_in[2];
    const float* w_proj = (const float*)d_in[3];
    const float* b_proj = (const float*)d_in[4];
    float* outp = (float*)d_out;
    char* ws = (char*)d_ws;

    // workspace layout (bytes)
    u16t* xb  = (u16t*)(ws + 0);          // 8192x1024 bf16 (x, later reused as attn_out)
    u16t* wta = (u16t*)(ws + 16777216);   // 3072x1024 bf16 (w_attn^T)
    u16t* wtp = (u16t*)(ws + 23068672);   // 1024x1024 bf16 (w_proj^T)
    u16t* qb  = (u16t*)(ws + 25165824);   // (B,H,T,64) bf16
    u16t* kb  = (u16t*)(ws + 41943040);   // (B,H,T,64) bf16
    u16t* vb  = (u16t*)(ws + 58720256);   // (B,H,T,64) bf16
    u16t* vtb = (u16t*)(ws + 75497472);   // (B,H,64,T) bf16
    if (ws_size < 92274688) return;       // loud failure rather than OOB writes

    cvt_f32_bf16<<<4096, 256, 0, stream>>>(x, xb, 8388608);
    transpose_w<<<dim3(96, 32), 256, 0, stream>>>(w_attn, wta, 1024, 3072);
    transpose_w<<<dim3(32, 32), 256, 0, stream>>>(w_proj, wtp, 1024, 1024);

    gemm_bt<1><<<dim3(64, 24), 256, 0, stream>>>(xb, wta, b_attn, nullptr, outp,
                                                 qb, kb, vb, 8192, 3072, 1024);
    transpose_v<<<dim3(64, 2, 64), 256, 0, stream>>>(vb, vtb);
    attn_fwd<<<dim3(64, 16), 256, 0, stream>>>(qb, kb, vtb, xb /* reuse as attn_out */);
    gemm_bt<0><<<dim3(64, 8), 256, 0, stream>>>(xb, wtp, b_proj, outp,
                                                nullptr, nullptr, nullptr, nullptr,
                                                8192, 1024, 1024);
}

// Round 3
// 228.100 us; speedup vs baseline: 1.5509x; 1.0087x over previous
//
#include <hip/hip_runtime.h>
#include <hip/hip_bf16.h>
#include <cstdint>
#include <cstddef>

typedef __bf16 y8 __attribute__((ext_vector_type(8)));
typedef float f4 __attribute__((ext_vector_type(4)));
typedef unsigned short u16t;

#define NB 4
#define TT 2048
#define DD 1024
#define HH 16

static constexpr size_t OUT0 = (size_t)NB * TT * DD;  // 8388608 floats (out), then present

__device__ __forceinline__ u16t bf16r(float f) {
    union { float f; unsigned u; } x; x.f = f;
    return (u16t)((x.u + 0x7FFFu + ((x.u >> 16) & 1u)) >> 16);
}

#define GLDS16(g, s) __builtin_amdgcn_global_load_lds( \
    (__attribute__((address_space(1))) void*)(g),      \
    (__attribute__((address_space(3))) void*)(s), 16, 0, 0)

// ---------------------------------------------------------------- conversions
__global__ __launch_bounds__(256)
void cvt_f32_bf16(const float* __restrict__ in, u16t* __restrict__ outp, int n) {
    int i = (blockIdx.x * 256 + threadIdx.x) * 8;
    if (i >= n) return;
    float4 a = *(const float4*)(in + i);
    float4 b = *(const float4*)(in + i + 4);
    union { u16t h[8]; uint4 q; } u;
    u.h[0] = bf16r(a.x); u.h[1] = bf16r(a.y); u.h[2] = bf16r(a.z); u.h[3] = bf16r(a.w);
    u.h[4] = bf16r(b.x); u.h[5] = bf16r(b.y); u.h[6] = bf16r(b.z); u.h[7] = bf16r(b.w);
    *(uint4*)(outp + i) = u.q;
}

// in: (Kd, Nd) f32 row-major -> out: (Nd, Kd) bf16 row-major
__global__ __launch_bounds__(256)
void transpose_w(const float* __restrict__ in, u16t* __restrict__ outp, int Kd, int Nd) {
    __shared__ float tile[32][33];
    const int n0 = blockIdx.x * 32, k0 = blockIdx.y * 32;
    const int tx = threadIdx.x & 31, ty = threadIdx.x >> 5;
    for (int yy = ty; yy < 32; yy += 8)
        tile[yy][tx] = in[(size_t)(k0 + yy) * Nd + n0 + tx];
    __syncthreads();
    for (int yy = ty; yy < 32; yy += 8)
        outp[(size_t)(n0 + yy) * Kd + k0 + tx] = bf16r(tile[tx][yy]);
}

// vb: (BH, T, 64) bf16 -> vt: (BH, 64, T) bf16
__global__ __launch_bounds__(256)
void transpose_v(const u16t* __restrict__ vb, u16t* __restrict__ vt) {
    __shared__ u16t tile[32][33];
    const int t0 = blockIdx.x * 32, d0 = blockIdx.y * 32, bh = blockIdx.z;
    const u16t* src = vb + (size_t)bh * TT * 64;
    u16t* dst = vt + (size_t)bh * 64 * TT;
    const int tx = threadIdx.x & 31, ty = threadIdx.x >> 5;
    for (int yy = ty; yy < 32; yy += 8)
        tile[yy][tx] = src[(t0 + yy) * 64 + d0 + tx];
    __syncthreads();
    for (int yy = ty; yy < 32; yy += 8)
        dst[(d0 + yy) * TT + t0 + tx] = tile[tx][yy];
}

// ---------------------------------------------------------------- GEMM
// C(M,N) f32 = A(M,K)bf16 * Bt(N,K)bf16^T + bias.
// 2-phase prefetch: double-buffered LDS, stage(t+1) issued before compute(t),
// one vmcnt(0)+barrier per K-tile (T3-minimum; m248v2: 666 TF @ K=1024).
// MODE 0: plain f32 C.  MODE 1: qkv epilogue (present f32 + head-layout bf16 q/k/v).
template<int MODE>
__global__ __launch_bounds__(256, 2)
void gemm_bt(const u16t* __restrict__ A, const u16t* __restrict__ Bt,
             const float* __restrict__ bias, float* __restrict__ C,
             float* __restrict__ pres, u16t* __restrict__ qb,
             u16t* __restrict__ kb, u16t* __restrict__ vb,
             int M, int N, int K)
{
    __shared__ u16t ldsA[2][128 * 64];
    __shared__ u16t ldsB[2][128 * 64];
    const int tid = threadIdx.x;
    const int w = tid >> 6, l = tid & 63;
    const int wr = w >> 1, wc = w & 1;
    const int lr = l & 15, lq = l >> 4;
    const int bm = blockIdx.x * 128;
    const int bn = blockIdx.y * 128;

    auto stage = [&](int k0, int pi) {
#pragma unroll
        for (int c = 0; c < 4; ++c) {
            const int L = ((w * 64 + l) << 4) + (c << 12);
            const int row = L >> 7;
            const int col = (((L >> 4) & 7) ^ (row & 7)) << 3;  // inverse-swizzled source
            GLDS16(A + (size_t)(bm + row) * K + k0 + col,
                   (char*)ldsA[pi] + (w << 10) + (c << 12));
            GLDS16(Bt + (size_t)(bn + row) * K + k0 + col,
                   (char*)ldsB[pi] + (w << 10) + (c << 12));
        }
    };

    f4 acc[4][4] = {};

    stage(0, 0);
    __syncthreads();
    int cur = 0;
    const int nt = K >> 6;
    for (int t = 0; t < nt; ++t) {
        if (t + 1 < nt) stage((t + 1) << 6, cur ^ 1);  // prefetch next tile
        const char* La = (const char*)ldsA[cur];
        const char* Lb = (const char*)ldsB[cur];
#pragma unroll
        for (int ks = 0; ks < 2; ++ks) {
            y8 af[4], bfv[4];
#pragma unroll
            for (int m = 0; m < 4; ++m) {
                const int row = wr * 64 + m * 16 + lr;
                const int slot = (lq + ks * 4) ^ (row & 7);
                af[m] = *(const y8*)(La + row * 128 + (slot << 4));
            }
#pragma unroll
            for (int n = 0; n < 4; ++n) {
                const int row = wc * 64 + n * 16 + lr;
                const int slot = (lq + ks * 4) ^ (row & 7);
                bfv[n] = *(const y8*)(Lb + row * 128 + (slot << 4));
            }
#pragma unroll
            for (int m = 0; m < 4; ++m)
#pragma unroll
                for (int n = 0; n < 4; ++n)
                    acc[m][n] = __builtin_amdgcn_mfma_f32_16x16x32_bf16(af[m], bfv[n], acc[m][n], 0, 0, 0);
        }
        __syncthreads();  // drains vmcnt(0) (prefetch landed) + waves done reading
        cur ^= 1;
    }

    if (MODE == 0) {
#pragma unroll
        for (int m = 0; m < 4; ++m) {
            const int rowb = bm + wr * 64 + m * 16 + 4 * lq;
#pragma unroll
            for (int n = 0; n < 4; ++n) {
                const int col = bn + wc * 64 + n * 16 + lr;
                const float bv = bias[col];
#pragma unroll
                for (int r = 0; r < 4; ++r)
                    C[(size_t)(rowb + r) * N + col] = acc[m][n][r] + bv;
            }
        }
    } else {
        const int part = bn >> 10;  // 0=q, 1=k, 2=v (128-col tiles never cross 1024 boundary)
#pragma unroll
        for (int m = 0; m < 4; ++m) {
            const int rowb = bm + wr * 64 + m * 16 + 4 * lq;
#pragma unroll
            for (int n = 0; n < 4; ++n) {
                const int colg = bn + wc * 64 + n * 16 + lr;
                const float bv = bias[colg];
                const int cl = colg & 1023;
                const int h = cl >> 6, d = cl & 63;
#pragma unroll
                for (int r = 0; r < 4; ++r) {
                    const int bt = rowb + r;
                    const int b = bt >> 11, t = bt & 2047;
                    const float val = acc[m][n][r] + bv;
                    const size_t hidx = (((size_t)(b * HH + h)) * TT + t) * 64 + d;
                    if (part == 0) {
                        qb[hidx] = bf16r(val);
                    } else if (part == 1) {
                        kb[hidx] = bf16r(val);
                        pres[OUT0 + (((size_t)((b * 2 + 0) * HH + h)) * TT + t) * 64 + d] = val;
                    } else {
                        vb[hidx] = bf16r(val);
                        pres[OUT0 + (((size_t)((b * 2 + 1) * HH + h)) * TT + t) * 64 + d] = val;
                    }
                }
            }
        }
    }
}

// ---------------------------------------------------------------- attention
// Block = (qt, bh): 128 q-rows, 4 waves x 32 rows (2 m-tiles each). KV tile 64,
// double-buffered (1 barrier per tile). Flash online softmax; lsum reduce deferred
// to epilogue (per-lane partials, row-uniform corr).
__global__ __launch_bounds__(256, 2)
void attn_fwd(const u16t* __restrict__ qg, const u16t* __restrict__ kg,
              const u16t* __restrict__ vtg, u16t* __restrict__ og)
{
    __shared__ u16t sQ[128 * 64];      // 16 KB
    __shared__ u16t sK[2 * 64 * 64];   // 16 KB (double buffer)
    __shared__ u16t sV[2 * 64 * 64];   // 16 KB
    __shared__ u16t sP[4 * 32 * 64];   // 16 KB (per-wave 32x64)
    const int tid = threadIdx.x;
    const int w = tid >> 6, l = tid & 63;
    const int lr = l & 15, lq = l >> 4;
    const int qt = 15 - blockIdx.y;    // long blocks first
    const int bh = blockIdx.x;
    const int b = bh >> 4, h = bh & 15;
    const u16t* qsrc = qg + (size_t)bh * TT * 64;
    const u16t* ksrc = kg + (size_t)bh * TT * 64;
    const u16t* vsrc = vtg + (size_t)bh * 64 * TT;

    auto stageKV = [&](int kt, int pi) {
        const int kv0 = kt << 6;
#pragma unroll
        for (int c = 0; c < 2; ++c) {
            const int L = ((w * 64 + l) << 4) + (c << 12);
            const int row = L >> 7;
            const int col = (((L >> 4) & 7) ^ (row & 7)) << 3;
            GLDS16(ksrc + (kv0 + row) * 64 + col,
                   (char*)sK + (pi << 13) + (w << 10) + (c << 12));
            GLDS16(vsrc + (size_t)row * TT + kv0 + col,
                   (char*)sV + (pi << 13) + (w << 10) + (c << 12));
        }
    };

    // stage Q tile (128 x 64) + KV tile 0
#pragma unroll
    for (int c = 0; c < 4; ++c) {
        const int L = ((w * 64 + l) << 4) + (c << 12);
        const int row = L >> 7;
        const int col = (((L >> 4) & 7) ^ (row & 7)) << 3;
        GLDS16(qsrc + (qt * 128 + row) * 64 + col, (char*)sQ + (w << 10) + (c << 12));
    }
    stageKV(0, 0);
    __syncthreads();

    y8 qf[2][2];
#pragma unroll
    for (int qm = 0; qm < 2; ++qm)
#pragma unroll
        for (int ks = 0; ks < 2; ++ks) {
            const int row = w * 32 + qm * 16 + lr;
            const int slot = (lq + ks * 4) ^ (row & 7);
            qf[qm][ks] = *(const y8*)((const char*)sQ + row * 128 + (slot << 4));
        }

    f4 o[2][4] = {};
    float mrow[2][4], lsum[2][4];
#pragma unroll
    for (int qm = 0; qm < 2; ++qm)
#pragma unroll
        for (int r = 0; r < 4; ++r) { mrow[qm][r] = -1e30f; lsum[qm][r] = 0.f; }

    char* Pw = (char*)sP + (w << 12);  // per-wave 32x64 bf16 region
    const int qmax = qt * 128 + w * 32 + 31;  // wave's last q-row
    const int ktiles = 2 * qt + 2;
    int cur = 0;

    for (int kt = 0; kt < ktiles; ++kt) {
        __syncthreads();  // buf[cur] staged; all waves done reading buf[cur^1]
        if (kt + 1 < ktiles) stageKV(kt + 1, cur ^ 1);
        const int kv0 = kt << 6;
        if (kv0 <= qmax) {  // tile not fully masked for this wave
            const char* Kb = (const char*)sK + (cur << 13);
            const char* Vb = (const char*)sV + (cur << 13);

            // S = Q K^T  (32 q-rows x 64 keys per wave)
            f4 s[2][4] = {};
#pragma unroll
            for (int ks = 0; ks < 2; ++ks) {
                y8 kf[4];
#pragma unroll
                for (int n = 0; n < 4; ++n) {
                    const int row = n * 16 + lr;
                    const int slot = (lq + ks * 4) ^ (row & 7);
                    kf[n] = *(const y8*)(Kb + row * 128 + (slot << 4));
                }
#pragma unroll
                for (int qm = 0; qm < 2; ++qm)
#pragma unroll
                    for (int n = 0; n < 4; ++n)
                        s[qm][n] = __builtin_amdgcn_mfma_f32_16x16x32_bf16(qf[qm][ks], kf[n], s[qm][n], 0, 0, 0);
            }

#pragma unroll
            for (int qm = 0; qm < 2; ++qm) {
                const int qb0 = qt * 128 + w * 32 + qm * 16;
                if (kv0 + 63 > qb0) {  // tile crosses diagonal for this m-tile
#pragma unroll
                    for (int n = 0; n < 4; ++n) {
                        const int kcol = kv0 + n * 16 + lr;
#pragma unroll
                        for (int r = 0; r < 4; ++r) {
                            const int qrow = qb0 + 4 * lq + r;
                            const float sv = s[qm][n][r] * 0.125f;
                            s[qm][n][r] = (kcol > qrow) ? -1e30f : sv;
                        }
                    }
                } else {
#pragma unroll
                    for (int n = 0; n < 4; ++n)
#pragma unroll
                        for (int r = 0; r < 4; ++r) s[qm][n][r] *= 0.125f;
                }

                // online softmax: max reduce across 16-lane row group; sum stays per-lane
#pragma unroll
                for (int r = 0; r < 4; ++r) {
                    float mx = fmaxf(fmaxf(s[qm][0][r], s[qm][1][r]),
                                     fmaxf(s[qm][2][r], s[qm][3][r]));
                    mx = fmaxf(mx, __shfl_xor(mx, 1));
                    mx = fmaxf(mx, __shfl_xor(mx, 2));
                    mx = fmaxf(mx, __shfl_xor(mx, 4));
                    mx = fmaxf(mx, __shfl_xor(mx, 8));
                    const float newm = fmaxf(mrow[qm][r], mx);
                    const float corr = __expf(mrow[qm][r] - newm);
                    mrow[qm][r] = newm;
                    float rs = 0.f;
#pragma unroll
                    for (int n = 0; n < 4; ++n) {
                        const float p = __expf(s[qm][n][r] - newm);
                        s[qm][n][r] = p;
                        rs += p;
                    }
                    lsum[qm][r] = lsum[qm][r] * corr + rs;
#pragma unroll
                    for (int n = 0; n < 4; ++n) o[qm][n][r] *= corr;
                }

                // P -> per-wave LDS (bf16, swizzled rows)
#pragma unroll
                for (int n = 0; n < 4; ++n)
#pragma unroll
                    for (int r = 0; r < 4; ++r) {
                        const int prow = qm * 16 + 4 * lq + r;
                        const int pb = (n * 16 + lr) * 2;
                        const int boff = prow * 128 + (((pb >> 4) ^ (prow & 7)) << 4) + (pb & 15);
                        *(u16t*)(Pw + boff) = bf16r(s[qm][n][r]);
                    }
            }

            // O += P V
#pragma unroll
            for (int ks = 0; ks < 2; ++ks) {
                y8 vf[4], pf[2];
#pragma unroll
                for (int n = 0; n < 4; ++n) {
                    const int row = n * 16 + lr;
                    const int slot = (lq + ks * 4) ^ (row & 7);
                    vf[n] = *(const y8*)(Vb + row * 128 + (slot << 4));
                }
#pragma unroll
                for (int qm = 0; qm < 2; ++qm) {
                    const int slotp = (lq + ks * 4) ^ (lr & 7);
                    pf[qm] = *(const y8*)(Pw + (qm * 16 + lr) * 128 + (slotp << 4));
                }
#pragma unroll
                for (int qm = 0; qm < 2; ++qm)
#pragma unroll
                    for (int n = 0; n < 4; ++n)
                        o[qm][n] = __builtin_amdgcn_mfma_f32_16x16x32_bf16(pf[qm], vf[n], o[qm][n], 0, 0, 0);
            }
        }
        cur ^= 1;
    }

    // epilogue: deferred lsum reduce + normalize + store
#pragma unroll
    for (int qm = 0; qm < 2; ++qm)
#pragma unroll
        for (int r = 0; r < 4; ++r) {
            float t = lsum[qm][r];
            t += __shfl_xor(t, 1);
            t += __shfl_xor(t, 2);
            t += __shfl_xor(t, 4);
            t += __shfl_xor(t, 8);
            const float inv = 1.0f / t;
            const int trow = qt * 128 + w * 32 + qm * 16 + 4 * lq + r;
#pragma unroll
            for (int n = 0; n < 4; ++n)
                og[((size_t)(b * TT + trow)) * DD + h * 64 + n * 16 + lr] =
                    bf16r(o[qm][n][r] * inv);
        }
}

// ---------------------------------------------------------------- launch
extern "C" void kernel_launch(void* const* d_in, const int* in_sizes, int n_in,
                              void* d_out, int out_size, void* d_ws, size_t ws_size,
                              hipStream_t stream) {
    const float* x      = (const float*)d_in[0];
    const float* w_attn = (const float*)d_in[1];
    const float* b_attn = (const float*)d_in[2];
    const float* w_proj = (const float*)d_in[3];
    const float* b_proj = (const float*)d_in[4];
    float* outp = (float*)d_out;
    char* ws = (char*)d_ws;

    // workspace layout (bytes)
    u16t* xb  = (u16t*)(ws + 0);          // 8192x1024 bf16 (x, later reused as attn_out)
    u16t* wta = (u16t*)(ws + 16777216);   // 3072x1024 bf16 (w_attn^T)
    u16t* wtp = (u16t*)(ws + 23068672);   // 1024x1024 bf16 (w_proj^T)
    u16t* qb  = (u16t*)(ws + 25165824);   // (B,H,T,64) bf16
    u16t* kb  = (u16t*)(ws + 41943040);   // (B,H,T,64) bf16
    u16t* vb  = (u16t*)(ws + 58720256);   // (B,H,T,64) bf16
    u16t* vtb = (u16t*)(ws + 75497472);   // (B,H,64,T) bf16
    if (ws_size < 92274688) return;       // loud failure rather than OOB writes

    cvt_f32_bf16<<<4096, 256, 0, stream>>>(x, xb, 8388608);
    transpose_w<<<dim3(96, 32), 256, 0, stream>>>(w_attn, wta, 1024, 3072);
    transpose_w<<<dim3(32, 32), 256, 0, stream>>>(w_proj, wtp, 1024, 1024);

    gemm_bt<1><<<dim3(64, 24), 256, 0, stream>>>(xb, wta, b_attn, nullptr, outp,
                                                 qb, kb, vb, 8192, 3072, 1024);
    transpose_v<<<dim3(64, 2, 64), 256, 0, stream>>>(vb, vtb);
    attn_fwd<<<dim3(64, 16), 256, 0, stream>>>(qb, kb, vtb, xb /* reuse as attn_out */);
    gemm_bt<0><<<dim3(64, 8), 256, 0, stream>>>(xb, wtp, b_proj, outp,
                                                nullptr, nullptr, nullptr, nullptr,
                                                8192, 1024, 1024);
}

// Round 4
// 195.460 us; speedup vs baseline: 1.8099x; 1.1670x over previous
//
#include <hip/hip_runtime.h>
#include <hip/hip_bf16.h>
#include <cstdint>
#include <cstddef>

typedef __bf16 y8 __attribute__((ext_vector_type(8)));
typedef float f4 __attribute__((ext_vector_type(4)));
typedef unsigned short u16t;

#define NB 4
#define TT 2048
#define DD 1024
#define HH 16

static constexpr size_t OUT0 = (size_t)NB * TT * DD;  // 8388608 floats (out), then present
#define QSCALE 0.180336880111120426f                  // 0.125 * log2(e): softmax in exp2 domain

__device__ __forceinline__ u16t bf16r(float f) {
    union { float f; unsigned u; } x; x.f = f;
    return (u16t)((x.u + 0x7FFFu + ((x.u >> 16) & 1u)) >> 16);
}

__device__ __forceinline__ unsigned cvtpk(float lo, float hi) {
    unsigned r;
    asm("v_cvt_pk_bf16_f32 %0, %1, %2" : "=v"(r) : "v"(lo), "v"(hi));
    return r;
}

#define GLDS16(g, s) __builtin_amdgcn_global_load_lds( \
    (__attribute__((address_space(1))) void*)(g),      \
    (__attribute__((address_space(3))) void*)(s), 16, 0, 0)

// ---------------------------------------------------------------- conversions
__global__ __launch_bounds__(256)
void cvt_f32_bf16(const float* __restrict__ in, u16t* __restrict__ outp, int n) {
    int i = (blockIdx.x * 256 + threadIdx.x) * 8;
    if (i >= n) return;
    float4 a = *(const float4*)(in + i);
    float4 b = *(const float4*)(in + i + 4);
    union { u16t h[8]; uint4 q; } u;
    u.h[0] = bf16r(a.x); u.h[1] = bf16r(a.y); u.h[2] = bf16r(a.z); u.h[3] = bf16r(a.w);
    u.h[4] = bf16r(b.x); u.h[5] = bf16r(b.y); u.h[6] = bf16r(b.z); u.h[7] = bf16r(b.w);
    *(uint4*)(outp + i) = u.q;
}

// in: (Kd, Nd) f32 row-major -> out: (Nd, Kd) bf16 row-major
__global__ __launch_bounds__(256)
void transpose_w(const float* __restrict__ in, u16t* __restrict__ outp, int Kd, int Nd) {
    __shared__ float tile[32][33];
    const int n0 = blockIdx.x * 32, k0 = blockIdx.y * 32;
    const int tx = threadIdx.x & 31, ty = threadIdx.x >> 5;
    for (int yy = ty; yy < 32; yy += 8)
        tile[yy][tx] = in[(size_t)(k0 + yy) * Nd + n0 + tx];
    __syncthreads();
    for (int yy = ty; yy < 32; yy += 8)
        outp[(size_t)(n0 + yy) * Kd + k0 + tx] = bf16r(tile[tx][yy]);
}

// ---------------------------------------------------------------- GEMM
// C(M,N) f32 = A(M,K)bf16 * Bt(N,K)bf16^T + bias.
// 2-phase prefetch: double-buffered LDS, stage(t+1) issued before compute(t),
// one vmcnt(0)+barrier per K-tile.
// MODE 0: plain f32 C.
// MODE 1: qkv epilogue: q scaled by QSCALE (softmax fold), k head-layout,
//         v written directly transposed (BH,64,T), present f32.
template<int MODE>
__global__ __launch_bounds__(256, 2)
void gemm_bt(const u16t* __restrict__ A, const u16t* __restrict__ Bt,
             const float* __restrict__ bias, float* __restrict__ C,
             float* __restrict__ pres, u16t* __restrict__ qb,
             u16t* __restrict__ kb, u16t* __restrict__ vtb,
             int M, int N, int K)
{
    __shared__ u16t ldsA[2][128 * 64];
    __shared__ u16t ldsB[2][128 * 64];
    const int tid = threadIdx.x;
    const int w = tid >> 6, l = tid & 63;
    const int wr = w >> 1, wc = w & 1;
    const int lr = l & 15, lq = l >> 4;
    const int bm = blockIdx.x * 128;
    const int bn = blockIdx.y * 128;

    auto stage = [&](int k0, int pi) {
#pragma unroll
        for (int c = 0; c < 4; ++c) {
            const int L = ((w * 64 + l) << 4) + (c << 12);
            const int row = L >> 7;
            const int col = (((L >> 4) & 7) ^ (row & 7)) << 3;  // inverse-swizzled source
            GLDS16(A + (size_t)(bm + row) * K + k0 + col,
                   (char*)ldsA[pi] + (w << 10) + (c << 12));
            GLDS16(Bt + (size_t)(bn + row) * K + k0 + col,
                   (char*)ldsB[pi] + (w << 10) + (c << 12));
        }
    };

    f4 acc[4][4] = {};

    stage(0, 0);
    __syncthreads();
    int cur = 0;
    const int nt = K >> 6;
    for (int t = 0; t < nt; ++t) {
        if (t + 1 < nt) stage((t + 1) << 6, cur ^ 1);  // prefetch next tile
        const char* La = (const char*)ldsA[cur];
        const char* Lb = (const char*)ldsB[cur];
#pragma unroll
        for (int ks = 0; ks < 2; ++ks) {
            y8 af[4], bfv[4];
#pragma unroll
            for (int m = 0; m < 4; ++m) {
                const int row = wr * 64 + m * 16 + lr;
                const int slot = (lq + ks * 4) ^ (row & 7);
                af[m] = *(const y8*)(La + row * 128 + (slot << 4));
            }
#pragma unroll
            for (int n = 0; n < 4; ++n) {
                const int row = wc * 64 + n * 16 + lr;
                const int slot = (lq + ks * 4) ^ (row & 7);
                bfv[n] = *(const y8*)(Lb + row * 128 + (slot << 4));
            }
#pragma unroll
            for (int m = 0; m < 4; ++m)
#pragma unroll
                for (int n = 0; n < 4; ++n)
                    acc[m][n] = __builtin_amdgcn_mfma_f32_16x16x32_bf16(af[m], bfv[n], acc[m][n], 0, 0, 0);
        }
        __syncthreads();  // drains vmcnt(0) (prefetch landed) + waves done reading
        cur ^= 1;
    }

    if (MODE == 0) {
#pragma unroll
        for (int m = 0; m < 4; ++m) {
            const int rowb = bm + wr * 64 + m * 16 + 4 * lq;
#pragma unroll
            for (int n = 0; n < 4; ++n) {
                const int col = bn + wc * 64 + n * 16 + lr;
                const float bv = bias[col];
#pragma unroll
                for (int r = 0; r < 4; ++r)
                    C[(size_t)(rowb + r) * N + col] = acc[m][n][r] + bv;
            }
        }
    } else {
        const int part = bn >> 10;  // 0=q, 1=k, 2=v (128-col tiles never cross 1024 boundary)
#pragma unroll
        for (int m = 0; m < 4; ++m) {
            const int rowb = bm + wr * 64 + m * 16 + 4 * lq;
            const int b0 = rowb >> 11, t0 = rowb & 2047;  // 4 rows never cross batch
#pragma unroll
            for (int n = 0; n < 4; ++n) {
                const int colg = bn + wc * 64 + n * 16 + lr;
                const float bv = bias[colg];
                const int cl = colg & 1023;
                const int h = cl >> 6, d = cl & 63;
                float vals[4];
#pragma unroll
                for (int r = 0; r < 4; ++r) vals[r] = acc[m][n][r] + bv;
                if (part == 0) {
#pragma unroll
                    for (int r = 0; r < 4; ++r)
                        qb[(((size_t)(b0 * HH + h)) * TT + t0 + r) * 64 + d] =
                            bf16r(vals[r] * QSCALE);
                } else if (part == 1) {
#pragma unroll
                    for (int r = 0; r < 4; ++r) {
                        kb[(((size_t)(b0 * HH + h)) * TT + t0 + r) * 64 + d] = bf16r(vals[r]);
                        pres[OUT0 + (((size_t)((b0 * 2 + 0) * HH + h)) * TT + t0 + r) * 64 + d] = vals[r];
                    }
                } else {
#pragma unroll
                    for (int r = 0; r < 4; ++r)
                        pres[OUT0 + (((size_t)((b0 * 2 + 1) * HH + h)) * TT + t0 + r) * 64 + d] = vals[r];
                    uint2 pk;
                    pk.x = cvtpk(vals[0], vals[1]);
                    pk.y = cvtpk(vals[2], vals[3]);
                    *(uint2*)(vtb + ((size_t)(b0 * HH + h) * 64 + d) * TT + t0) = pk;
                }
            }
        }
    }
}

// ---------------------------------------------------------------- attention
// Block = (qt, bh): 128 q-rows, 4 waves x 32 rows. KV tile 64, double-buffered.
// SWAPPED operands: S = mfma(K,Q) so softmax state is per-lane (query = lane&15);
// O = mfma(V,P) keeps query = lane&15. Softmax in exp2 domain (scale folded into Q).
// T13 defer-max (THR=8). P routed via per-wave swizzled LDS (b64 packed writes).
__global__ __launch_bounds__(256, 2)
void attn_fwd(const u16t* __restrict__ qg, const u16t* __restrict__ kg,
              const u16t* __restrict__ vtg, u16t* __restrict__ og)
{
    __shared__ u16t sQ[128 * 64];      // 16 KB
    __shared__ u16t sK[2 * 64 * 64];   // 16 KB (double buffer)
    __shared__ u16t sV[2 * 64 * 64];   // 16 KB
    __shared__ u16t sP[4 * 32 * 64];   // 16 KB (per-wave 32x64)
    const int tid = threadIdx.x;
    const int w = tid >> 6, l = tid & 63;
    const int lr = l & 15, lq = l >> 4;
    const int qt = 15 - blockIdx.y;    // long blocks first
    const int bh = blockIdx.x;
    const int b = bh >> 4, h = bh & 15;
    const u16t* qsrc = qg + (size_t)bh * TT * 64;
    const u16t* ksrc = kg + (size_t)bh * TT * 64;
    const u16t* vsrc = vtg + (size_t)bh * 64 * TT;

    auto stageKV = [&](int kt, int pi) {
        const int kv0 = kt << 6;
#pragma unroll
        for (int c = 0; c < 2; ++c) {
            const int L = ((w * 64 + l) << 4) + (c << 12);
            const int row = L >> 7;
            const int col = (((L >> 4) & 7) ^ (row & 7)) << 3;
            GLDS16(ksrc + (kv0 + row) * 64 + col,
                   (char*)sK + (pi << 13) + (w << 10) + (c << 12));
            GLDS16(vsrc + (size_t)row * TT + kv0 + col,
                   (char*)sV + (pi << 13) + (w << 10) + (c << 12));
        }
    };

    // stage Q tile (128 x 64) + KV tile 0
#pragma unroll
    for (int c = 0; c < 4; ++c) {
        const int L = ((w * 64 + l) << 4) + (c << 12);
        const int row = L >> 7;
        const int col = (((L >> 4) & 7) ^ (row & 7)) << 3;
        GLDS16(qsrc + (qt * 128 + row) * 64 + col, (char*)sQ + (w << 10) + (c << 12));
    }
    stageKV(0, 0);
    __syncthreads();

    y8 qf[2][2];
#pragma unroll
    for (int qm = 0; qm < 2; ++qm)
#pragma unroll
        for (int ks = 0; ks < 2; ++ks) {
            const int row = w * 32 + qm * 16 + lr;
            const int slot = (lq + ks * 4) ^ (row & 7);
            qf[qm][ks] = *(const y8*)((const char*)sQ + row * 128 + (slot << 4));
        }

    f4 o[2][4] = {};
    float mrow[2] = {-1e30f, -1e30f};
    float lsum[2] = {0.f, 0.f};

    char* Pw = (char*)sP + (w << 12);  // per-wave 32x64 bf16 region
    const int qmax = qt * 128 + w * 32 + 31;  // wave's last q-row
    const int ktiles = 2 * qt + 2;
    int cur = 0;

    for (int kt = 0; kt < ktiles; ++kt) {
        __syncthreads();  // buf[cur] staged; all waves done reading buf[cur^1]
        if (kt + 1 < ktiles) stageKV(kt + 1, cur ^ 1);
        const int kv0 = kt << 6;
        if (kv0 <= qmax) {  // tile not fully masked for this wave
            const char* Kb = (const char*)sK + (cur << 13);
            const char* Vb = (const char*)sV + (cur << 13);

            // S^T tiles: s[qm][n] = mfma(K,Q): lane holds S[key n*16+4lq+r][query lane&15]
            f4 s[2][4] = {};
            __builtin_amdgcn_s_setprio(1);
#pragma unroll
            for (int ks = 0; ks < 2; ++ks) {
                y8 kf[4];
#pragma unroll
                for (int n = 0; n < 4; ++n) {
                    const int row = n * 16 + lr;
                    const int slot = (lq + ks * 4) ^ (row & 7);
                    kf[n] = *(const y8*)(Kb + row * 128 + (slot << 4));
                }
#pragma unroll
                for (int qm = 0; qm < 2; ++qm)
#pragma unroll
                    for (int n = 0; n < 4; ++n)
                        s[qm][n] = __builtin_amdgcn_mfma_f32_16x16x32_bf16(kf[n], qf[qm][ks], s[qm][n], 0, 0, 0);
            }
            __builtin_amdgcn_s_setprio(0);

#pragma unroll
            for (int qm = 0; qm < 2; ++qm) {
                const int qb0 = qt * 128 + w * 32 + qm * 16;
                if (kv0 + 63 > qb0) {  // tile crosses diagonal for this m-tile
                    const int query = qb0 + lr;
#pragma unroll
                    for (int n = 0; n < 4; ++n)
#pragma unroll
                        for (int r = 0; r < 4; ++r)
                            if (kv0 + n * 16 + 4 * lq + r > query) s[qm][n][r] = -1e30f;
                }

                // per-lane row max (query = lane&15): in-lane tree + 2 shfls
                float mx = -1e30f;
#pragma unroll
                for (int n = 0; n < 4; ++n)
                    mx = fmaxf(mx, fmaxf(fmaxf(s[qm][n][0], s[qm][n][1]),
                                         fmaxf(s[qm][n][2], s[qm][n][3])));
                mx = fmaxf(mx, __shfl_xor(mx, 16));
                mx = fmaxf(mx, __shfl_xor(mx, 32));

                // T13 defer-max: rescale only when max grows past THR=8 (exp2 domain)
                if (!__all(mx <= mrow[qm] + 8.f)) {
                    const float newm = fmaxf(mrow[qm], mx);
                    const float corr = exp2f(mrow[qm] - newm);
                    mrow[qm] = newm;
                    lsum[qm] *= corr;
#pragma unroll
                    for (int n = 0; n < 4; ++n) o[qm][n] *= corr;
                }

                float rs = 0.f;
#pragma unroll
                for (int n = 0; n < 4; ++n)
#pragma unroll
                    for (int r = 0; r < 4; ++r) {
                        const float p = exp2f(s[qm][n][r] - mrow[qm]);
                        s[qm][n][r] = p;
                        rs += p;
                    }
                lsum[qm] += rs;

                // P -> per-wave LDS: keys contiguous over r -> packed b64 writes
                const int prow = qm * 16 + lr;
                const int rbase = prow * 128 + ((lq & 1) << 3);
#pragma unroll
                for (int n = 0; n < 4; ++n) {
                    uint2 pk;
                    pk.x = cvtpk(s[qm][n][0], s[qm][n][1]);
                    pk.y = cvtpk(s[qm][n][2], s[qm][n][3]);
                    const int sIdx = 2 * n + (lq >> 1);
                    *(uint2*)(Pw + rbase + ((sIdx ^ (prow & 7)) << 4)) = pk;
                }
            }

            // O += V^T x P (swapped): lane holds O[d=n*16+4lq+r][query lane&15]
            __builtin_amdgcn_s_setprio(1);
#pragma unroll
            for (int ks = 0; ks < 2; ++ks) {
                y8 vf[4], pf[2];
#pragma unroll
                for (int n = 0; n < 4; ++n) {
                    const int row = n * 16 + lr;
                    const int slot = (lq + ks * 4) ^ (row & 7);
                    vf[n] = *(const y8*)(Vb + row * 128 + (slot << 4));
                }
#pragma unroll
                for (int qm = 0; qm < 2; ++qm) {
                    const int row = qm * 16 + lr;
                    const int slot = (lq + ks * 4) ^ (row & 7);
                    pf[qm] = *(const y8*)(Pw + row * 128 + (slot << 4));
                }
#pragma unroll
                for (int qm = 0; qm < 2; ++qm)
#pragma unroll
                    for (int n = 0; n < 4; ++n)
                        o[qm][n] = __builtin_amdgcn_mfma_f32_16x16x32_bf16(vf[n], pf[qm], o[qm][n], 0, 0, 0);
            }
            __builtin_amdgcn_s_setprio(0);
        }
        cur ^= 1;
    }

    // epilogue: lsum reduce (2 shfls), normalize, packed bf16 store
#pragma unroll
    for (int qm = 0; qm < 2; ++qm) {
        float t = lsum[qm];
        t += __shfl_xor(t, 16);
        t += __shfl_xor(t, 32);
        const float inv = 1.0f / t;
        const int trow = qt * 128 + w * 32 + qm * 16 + lr;
#pragma unroll
        for (int n = 0; n < 4; ++n) {
            uint2 pk;
            pk.x = cvtpk(o[qm][n][0] * inv, o[qm][n][1] * inv);
            pk.y = cvtpk(o[qm][n][2] * inv, o[qm][n][3] * inv);
            *(uint2*)(og + ((size_t)(b * TT + trow)) * DD + h * 64 + n * 16 + 4 * lq) = pk;
        }
    }
}

// ---------------------------------------------------------------- launch
extern "C" void kernel_launch(void* const* d_in, const int* in_sizes, int n_in,
                              void* d_out, int out_size, void* d_ws, size_t ws_size,
                              hipStream_t stream) {
    const float* x      = (const float*)d_in[0];
    const float* w_attn = (const float*)d_in[1];
    const float* b_attn = (const float*)d_in[2];
    const float* w_proj = (const float*)d_in[3];
    const float* b_proj = (const float*)d_in[4];
    float* outp = (float*)d_out;
    char* ws = (char*)d_ws;

    // workspace layout (bytes)
    u16t* xb  = (u16t*)(ws + 0);          // 8192x1024 bf16 (x, later reused as attn_out)
    u16t* wta = (u16t*)(ws + 16777216);   // 3072x1024 bf16 (w_attn^T)
    u16t* wtp = (u16t*)(ws + 23068672);   // 1024x1024 bf16 (w_proj^T)
    u16t* qb  = (u16t*)(ws + 25165824);   // (B,H,T,64) bf16, pre-scaled by QSCALE
    u16t* kb  = (u16t*)(ws + 41943040);   // (B,H,T,64) bf16
    u16t* vtb = (u16t*)(ws + 58720256);   // (B,H,64,T) bf16 (written transposed by GEMM)
    if (ws_size < 75497472) return;       // loud failure rather than OOB writes

    cvt_f32_bf16<<<4096, 256, 0, stream>>>(x, xb, 8388608);
    transpose_w<<<dim3(96, 32), 256, 0, stream>>>(w_attn, wta, 1024, 3072);
    transpose_w<<<dim3(32, 32), 256, 0, stream>>>(w_proj, wtp, 1024, 1024);

    gemm_bt<1><<<dim3(64, 24), 256, 0, stream>>>(xb, wta, b_attn, nullptr, outp,
                                                 qb, kb, vtb, 8192, 3072, 1024);
    attn_fwd<<<dim3(64, 16), 256, 0, stream>>>(qb, kb, vtb, xb /* reuse as attn_out */);
    gemm_bt<0><<<dim3(64, 8), 256, 0, stream>>>(xb, wtp, b_proj, outp,
                                                nullptr, nullptr, nullptr, nullptr,
                                                8192, 1024, 1024);
}